// Round 1
// baseline (55.714 us; speedup 1.0000x reference)
//
#include <hip/hip_runtime.h>
#include <stdint.h>

// Problem constants (fixed by reference: N=64, I=8192, D=128, K=16)
#define NB 64
#define NI 8192
#define ND 128
#define NK 16
#define PTS_PER_BLOCK 256
#define BLOCKS_PER_BATCH (NI / PTS_PER_BLOCK)   // 32
#define OUT_ELEMS (NB * NK * ND)                // 131072
#define MAPPED_NEG_INF 0x007FFFFFu              // map(-inf): ~0xFF800000

// Order-preserving float->uint map: max(float) == umax(mapped)
__device__ __forceinline__ uint32_t map_f32(float f) {
    uint32_t b = __float_as_uint(f);
    return b ^ ((uint32_t)((int32_t)b >> 31) | 0x80000000u);
}

__global__ __launch_bounds__(256) void seg_init(uint32_t* __restrict__ out) {
    int idx = blockIdx.x * 256 + threadIdx.x;
    out[idx] = MAPPED_NEG_INF;
}

__global__ __launch_bounds__(256, 8) void seg_max_kernel(
        const float* __restrict__ x,
        const int* __restrict__ ci,
        uint32_t* __restrict__ out) {
    __shared__ uint32_t loc[NK * ND];       // 8 KB, swizzled layout (see below)
    __shared__ int cidx[PTS_PER_BLOCK];     // 1 KB

    const int t = threadIdx.x;
    const int b = blockIdx.x;
    const int batch = b >> 5;                       // / BLOCKS_PER_BATCH
    const int chunk = (b & (BLOCKS_PER_BATCH - 1)) * PTS_PER_BLOCK;
    const int row0 = batch * NI + chunk;

    // init LDS accumulator
    for (int i = t; i < NK * ND; i += 256) loc[i] = MAPPED_NEG_INF;
    // stage cluster indices, rebased to this batch
    cidx[t] = ci[row0 + t] - batch * NK;
    __syncthreads();

    // Thread layout: lane32 = t&31 owns d = lane32*4 .. lane32*4+3 (one float4),
    // rsub = t>>5 gives 8 rows per iteration.
    const int lane32 = t & 31;
    const int rsub = t >> 5;

    const float4* xrow = (const float4*)(x + (size_t)row0 * ND) + lane32;

    // LDS swizzle: element (c, d) stored at loc[c*128 + (d&3)*32 + (d>>2)]
    // -> for this thread's 4 elems: base = c*128 + lane32, offsets {0,32,64,96}
    // -> atomic bank = lane32: conflict-free within a half-wave.
    for (int it = 0; it < PTS_PER_BLOCK / 8; ++it) {
        const int i = it * 8 + rsub;
        const int c = cidx[i];
        float4 v = xrow[(size_t)i * (ND / 4)];
        uint32_t m0 = map_f32(v.x);
        uint32_t m1 = map_f32(v.y);
        uint32_t m2 = map_f32(v.z);
        uint32_t m3 = map_f32(v.w);
        if ((unsigned)c < (unsigned)NK) {
            uint32_t* lp = &loc[(c << 7) + lane32];
            atomicMax(&lp[0],  m0);
            atomicMax(&lp[32], m1);
            atomicMax(&lp[64], m2);
            atomicMax(&lp[96], m3);
        }
    }
    __syncthreads();

    // Merge block-local maxima into global (un-swizzle on read).
    uint32_t* ob = out + (size_t)batch * (NK * ND);
    for (int o = t; o < NK * ND; o += 256) {
        const int c = o >> 7;
        const int d = o & 127;
        const int li = (c << 7) + ((d & 3) << 5) + (d >> 2);
        uint32_t v = loc[li];
        if (v != MAPPED_NEG_INF) atomicMax(&ob[o], v);
    }
}

__global__ __launch_bounds__(256) void seg_decode(uint32_t* __restrict__ out) {
    int idx = blockIdx.x * 256 + threadIdx.x;
    uint32_t m = out[idx];
    uint32_t b = (m & 0x80000000u) ? (m ^ 0x80000000u) : ~m;
    out[idx] = b;
}

extern "C" void kernel_launch(void* const* d_in, const int* in_sizes, int n_in,
                              void* d_out, int out_size, void* d_ws, size_t ws_size,
                              hipStream_t stream) {
    const float* x = (const float*)d_in[0];
    const int* ci = (const int*)d_in[1];
    uint32_t* out = (uint32_t*)d_out;

    seg_init<<<OUT_ELEMS / 256, 256, 0, stream>>>(out);
    seg_max_kernel<<<NB * BLOCKS_PER_BATCH, 256, 0, stream>>>(x, ci, out);
    seg_decode<<<OUT_ELEMS / 256, 256, 0, stream>>>(out);
}

// Round 2
// 52.948 us; speedup vs baseline: 1.0522x; 1.0522x over previous
//
#include <hip/hip_runtime.h>
#include <stdint.h>

// Problem constants (fixed by reference: N=64, I=8192, D=128, K=16)
#define NB 64
#define NI 8192
#define ND 128
#define NK 16
#define SEG (NK * ND)                 // 2048 elems per batch's output
#define OUT_ELEMS (NB * SEG)          // 131072
#define MAPPED_NEG_INF 0x007FFFFFu    // map(-inf)

// ---- Path A (workspace, 2 kernels, no atomics) ----
#define PPB_A 512
#define BPB_A (NI / PPB_A)            // 16 blocks per batch
#define GRID_A (NB * BPB_A)           // 1024
#define WS_NEEDED ((size_t)GRID_A * SEG * 4)  // 8 MB

// ---- Path B (fallback: 3 kernels, global atomics) ----
#define PPB_B 256
#define BPB_B (NI / PPB_B)            // 32

// Order-preserving float->uint map: max(float) == umax(mapped)
__device__ __forceinline__ uint32_t map_f32(float f) {
    uint32_t b = __float_as_uint(f);
    return b ^ ((uint32_t)((int32_t)b >> 31) | 0x80000000u);
}
__device__ __forceinline__ uint32_t unmap_u32(uint32_t m) {
    return (m & 0x80000000u) ? (m ^ 0x80000000u) : ~m;
}

// ================= Path A =================
__global__ __launch_bounds__(256, 4) void seg_partial(
        const float* __restrict__ x,
        const int* __restrict__ ci,
        uint32_t* __restrict__ ws) {
    __shared__ uint32_t loc[SEG];     // 8 KB, swizzled: (c,d) -> c*128 + (d&3)*32 + (d>>2)
    __shared__ int cidx[PPB_A];       // 2 KB

    const int t = threadIdx.x;
    const int b = blockIdx.x;
    const int batch = b >> 4;                         // / BPB_A
    const int chunk = (b & (BPB_A - 1)) * PPB_A;
    const int row0 = batch * NI + chunk;

    for (int i = t; i < SEG; i += 256) loc[i] = MAPPED_NEG_INF;
    for (int i = t; i < PPB_A; i += 256) cidx[i] = ci[row0 + i] - batch * NK;
    __syncthreads();

    const int lane32 = t & 31;
    const int rsub = t >> 5;
    const float4* xrow = (const float4*)(x + (size_t)row0 * ND) + lane32;

    // Atomic bank = lane32 for all four updates -> conflict-free per half-wave.
    #pragma unroll 2
    for (int it = 0; it < PPB_A / 8; ++it) {
        const int i = it * 8 + rsub;
        const int c = cidx[i];
        float4 v = xrow[(size_t)i * (ND / 4)];
        uint32_t* lp = &loc[(c << 7) + lane32];
        atomicMax(&lp[0],  map_f32(v.x));
        atomicMax(&lp[32], map_f32(v.y));
        atomicMax(&lp[64], map_f32(v.z));
        atomicMax(&lp[96], map_f32(v.w));
    }
    __syncthreads();

    // Plain coalesced store of un-swizzled partials (overwrites any poison; no init needed).
    uint32_t* wb = ws + (size_t)b * SEG;
    for (int o = t; o < SEG; o += 256) {
        const int c = o >> 7;
        const int d = o & 127;
        wb[o] = loc[(c << 7) + ((d & 3) << 5) + (d >> 2)];
    }
}

__global__ __launch_bounds__(256) void seg_reduce(
        const uint32_t* __restrict__ ws,
        uint32_t* __restrict__ out) {
    const int idx = blockIdx.x * 256 + threadIdx.x;   // 0..OUT_ELEMS-1
    const int batch = idx >> 11;                      // / SEG
    const int o = idx & (SEG - 1);
    const uint32_t* p = ws + (size_t)batch * BPB_A * SEG + o;
    uint32_t m = MAPPED_NEG_INF;
    #pragma unroll
    for (int j = 0; j < BPB_A; ++j) m = max(m, p[(size_t)j * SEG]);
    out[idx] = unmap_u32(m);
}

// ================= Path B (R0 fallback) =================
__global__ __launch_bounds__(256) void seg_init(uint32_t* __restrict__ out) {
    int idx = blockIdx.x * 256 + threadIdx.x;
    out[idx] = MAPPED_NEG_INF;
}

__global__ __launch_bounds__(256, 8) void seg_max_kernel(
        const float* __restrict__ x,
        const int* __restrict__ ci,
        uint32_t* __restrict__ out) {
    __shared__ uint32_t loc[SEG];
    __shared__ int cidx[PPB_B];

    const int t = threadIdx.x;
    const int b = blockIdx.x;
    const int batch = b >> 5;
    const int chunk = (b & (BPB_B - 1)) * PPB_B;
    const int row0 = batch * NI + chunk;

    for (int i = t; i < SEG; i += 256) loc[i] = MAPPED_NEG_INF;
    cidx[t] = ci[row0 + t] - batch * NK;
    __syncthreads();

    const int lane32 = t & 31;
    const int rsub = t >> 5;
    const float4* xrow = (const float4*)(x + (size_t)row0 * ND) + lane32;

    for (int it = 0; it < PPB_B / 8; ++it) {
        const int i = it * 8 + rsub;
        const int c = cidx[i];
        float4 v = xrow[(size_t)i * (ND / 4)];
        uint32_t* lp = &loc[(c << 7) + lane32];
        atomicMax(&lp[0],  map_f32(v.x));
        atomicMax(&lp[32], map_f32(v.y));
        atomicMax(&lp[64], map_f32(v.z));
        atomicMax(&lp[96], map_f32(v.w));
    }
    __syncthreads();

    uint32_t* ob = out + (size_t)batch * SEG;
    for (int o = t; o < SEG; o += 256) {
        const int c = o >> 7;
        const int d = o & 127;
        uint32_t v = loc[(c << 7) + ((d & 3) << 5) + (d >> 2)];
        if (v != MAPPED_NEG_INF) atomicMax(&ob[o], v);
    }
}

__global__ __launch_bounds__(256) void seg_decode(uint32_t* __restrict__ out) {
    int idx = blockIdx.x * 256 + threadIdx.x;
    out[idx] = unmap_u32(out[idx]);
}

extern "C" void kernel_launch(void* const* d_in, const int* in_sizes, int n_in,
                              void* d_out, int out_size, void* d_ws, size_t ws_size,
                              hipStream_t stream) {
    const float* x = (const float*)d_in[0];
    const int* ci = (const int*)d_in[1];
    uint32_t* out = (uint32_t*)d_out;

    if (ws_size >= WS_NEEDED) {
        uint32_t* ws = (uint32_t*)d_ws;
        seg_partial<<<GRID_A, 256, 0, stream>>>(x, ci, ws);
        seg_reduce<<<OUT_ELEMS / 256, 256, 0, stream>>>(ws, out);
    } else {
        seg_init<<<OUT_ELEMS / 256, 256, 0, stream>>>(out);
        seg_max_kernel<<<NB * BPB_B, 256, 0, stream>>>(x, ci, out);
        seg_decode<<<OUT_ELEMS / 256, 256, 0, stream>>>(out);
    }
}